// Round 8
// baseline (146.419 us; speedup 1.0000x reference)
//
#include <hip/hip_runtime.h>
#include <hip/hip_bf16.h>

#define CIN   64
#define HH_   56
#define WW_   56
#define FOUT  128
#define NN    32
#define SW    4
#define WB    14
#define HB    14                     // output rows per tile
#define NW    (SW*9*FOUT*CIN)        // 294912 weights
#define QWT_PER_B (8*9*2*64*8)       // 73728 shorts per stripe

typedef __attribute__((ext_vector_type(8))) short bf16x8;
typedef __attribute__((ext_vector_type(4))) float f32x4;

__device__ inline unsigned short f2bf(float x) {
    unsigned u = __float_as_uint(x);
    return (unsigned short)((u + 0x7FFFu + ((u >> 16) & 1u)) >> 16);  // RNE
}

// ---------- kernel 1: partial absmax ----------
__global__ void absmax_part(const float* __restrict__ w, float* __restrict__ part) {
    __shared__ float sm[4];
    int tid = threadIdx.x;
    float m = 0.f;
    for (int idx = blockIdx.x * 256 + tid; idx < NW; idx += 64 * 256)
        m = fmaxf(m, fabsf(w[idx]));
    #pragma unroll
    for (int off = 32; off > 0; off >>= 1)
        m = fmaxf(m, __shfl_down(m, off, 64));
    if ((tid & 63) == 0) sm[tid >> 6] = m;
    __syncthreads();
    if (tid == 0)
        part[blockIdx.x] = fmaxf(fmaxf(sm[0], sm[1]), fmaxf(sm[2], sm[3]));
}

// ---------- kernel 2: quant + pack into MFMA A-fragment order ----------
// layout: qwt[b][ft][t][cc][lane][8]; content = qw[f = ft*16+(lane&15)]
//         [c = cc*32 + (lane>>4)*8 + r] for tap t.
__global__ void quant_pack(const float* __restrict__ w, const float* __restrict__ part,
                           unsigned short* __restrict__ qwt) {
    float pm = part[threadIdx.x & 63];
    #pragma unroll
    for (int off = 1; off < 64; off <<= 1)
        pm = fmaxf(pm, __shfl_xor(pm, off, 64));
    float scale = pm / 7.0f;
    int o = blockIdx.x * 256 + threadIdx.x;
    if (o >= NW) return;
    int r    = o & 7;
    int lane = (o >> 3) & 63;
    int cc   = (o >> 9) & 1;
    int idx  = o >> 10;            // b*72 + ft*9 + t
    int t    = idx % 9;
    int ft   = (idx / 9) & 7;
    int b    = idx / 72;
    int f = ft * 16 + (lane & 15);
    int c = cc * 32 + (lane >> 4) * 8 + r;
    float v = w[((b * CIN + c) * 9 + t) * FOUT + f];   // orig p = c*9 + t
    qwt[o] = f2bf(rintf(v / scale) * scale);
}

// ---------- kernel 3: persistent-stripe conv, 2 tiles/block, T14 pipeline ----------
// grid (2, 32, 4): block owns stripe b, tiles hgb = 2*hp, 2*hp+1 (14 rows each).
// 8 waves = (wf 0..3, wp 0..1); wave: f-tiles {2wf,2wf+1} x 7 rows.
__global__ __launch_bounds__(512, 2)
void conv_mfma(const float* __restrict__ in,           // [N][C][H][W] f32
               const unsigned short* __restrict__ qwt, // packed A-fragments
               const float* __restrict__ bias,
               float* __restrict__ out) {              // [N][F][H][W] f32
    const int hp = blockIdx.x, n = blockIdx.y, b = blockIdx.z;
    const int w0 = b * WB;
    const int h0a = hp * 2 * HB, h0b = h0a + HB;
    const int tid = threadIdx.x;
    const int wave = tid >> 6, lane = tid & 63;
    const int q = lane >> 4, lm = lane & 15;
    const int wf = wave >> 1, wp = wave & 1;

    __shared__ __align__(16) unsigned short s_slab[2][256 * 64];   // 2 x 32 KiB

    // ---- weight A-fragments: loaded once, LIVE ACROSS BOTH TILES ----
    const unsigned short* wbase = qwt + (size_t)b * QWT_PER_B + lane * 8;
    bf16x8 wt[2][9][2];
    #pragma unroll
    for (int m = 0; m < 2; ++m)
        #pragma unroll
        for (int t = 0; t < 9; ++t)
            #pragma unroll
            for (int cc = 0; cc < 2; ++cc)
                wt[m][t][cc] = *(const bf16x8*)&wbase[((((wf * 2 + m) * 9) + t) * 2 + cc) * 512];

    // per-thread staging coords (same for both tiles)
    // e = i*512+tid: cp=e&15 (col), c0=((e>>4)&31)*2 (ch pair), row=e>>9 (0..15)
    auto stage_load = [&](int h0, float (&r0)[16], float (&r1)[16]) {
        #pragma unroll
        for (int i = 0; i < 16; ++i) {
            int e = i * 512 + tid;
            int cp = e & 15, c0 = ((e >> 4) & 31) * 2, row = e >> 9;
            int hi = h0 - 1 + row, wi = w0 - 1 + cp;
            float v0 = 0.f, v1 = 0.f;
            if (hi >= 0 && hi < HH_ && wi >= 0 && wi < WW_) {
                const float* p = &in[((n * CIN + c0) * HH_ + hi) * WW_ + wi];
                v0 = p[0]; v1 = p[HH_ * WW_];
            }
            r0[i] = v0; r1[i] = v1;
        }
    };
    auto stage_write = [&](int bi, float (&r0)[16], float (&r1)[16]) {
        #pragma unroll
        for (int i = 0; i < 16; ++i) {
            int e = i * 512 + tid;
            int cp = e & 15, c0 = ((e >> 4) & 31) * 2, row = e >> 9;
            unsigned pk = (unsigned)f2bf(r0[i]) | ((unsigned)f2bf(r1[i]) << 16);
            int pix = row * 16 + cp;
            *(unsigned*)&s_slab[bi][pix * 64 + (c0 ^ ((cp & 7) << 3))] = pk;
        }
    };
    auto kloop = [&](int bi, f32x4 (&acc)[2][7]) {
        #pragma unroll
        for (int t = 0; t < 9; ++t) {
            const int kh = t / 3, kw = t - (t / 3) * 3;
            const int sc  = (lm + kw) & 15;
            const int swz = (sc & 7) << 3;
            #pragma unroll
            for (int cc = 0; cc < 2; ++cc) {
                const int koff = cc * 32 + q * 8;
                bf16x8 bfr[7];
                #pragma unroll
                for (int p = 0; p < 7; ++p) {
                    int srow = wp * 7 + p + kh;
                    bfr[p] = *(const bf16x8*)&s_slab[bi][(srow * 16 + sc) * 64 + (koff ^ swz)];
                }
                #pragma unroll
                for (int m = 0; m < 2; ++m)
                    #pragma unroll
                    for (int p = 0; p < 7; ++p)
                        acc[m][p] = __builtin_amdgcn_mfma_f32_16x16x32_bf16(
                            wt[m][t][cc], bfr[p], acc[m][p], 0, 0, 0);
            }
        }
    };
    auto epilogue = [&](int h0, f32x4 (&acc)[2][7]) {
        if (lm < WB) {
            #pragma unroll
            for (int m = 0; m < 2; ++m) {
                #pragma unroll
                for (int r = 0; r < 4; ++r) {
                    int f = (wf * 2 + m) * 16 + q * 4 + r;
                    float bv = bias[f];
                    float* op = &out[(((size_t)n * FOUT + f) * HH_ + h0 + wp * 7) * WW_ + w0 + lm];
                    #pragma unroll
                    for (int p = 0; p < 7; ++p)
                        op[p * WW_] = acc[m][p][r] + bv;
                }
            }
        }
    };

    // ---- tile 0 stage; tile 1 loads issued early (latency hides under K-loop 0) ----
    float va0[16], va1[16], vb0[16], vb1[16];
    stage_load(h0a, va0, va1);
    stage_write(0, va0, va1);
    stage_load(h0b, vb0, vb1);          // in flight across K-loop 0

    asm volatile("s_waitcnt lgkmcnt(0)" ::: "memory");
    __builtin_amdgcn_s_barrier();       // slab0 ready (no vmcnt drain!)

    f32x4 acc[2][7];
    #pragma unroll
    for (int m = 0; m < 2; ++m)
        #pragma unroll
        for (int p = 0; p < 7; ++p)
            acc[m][p] = (f32x4){0.f, 0.f, 0.f, 0.f};

    kloop(0, acc);
    epilogue(h0a, acc);

    #pragma unroll
    for (int m = 0; m < 2; ++m)
        #pragma unroll
        for (int p = 0; p < 7; ++p)
            acc[m][p] = (f32x4){0.f, 0.f, 0.f, 0.f};

    stage_write(1, vb0, vb1);           // values long since landed
    asm volatile("s_waitcnt lgkmcnt(0)" ::: "memory");
    __builtin_amdgcn_s_barrier();       // slab1 ready

    kloop(1, acc);
    epilogue(h0b, acc);
}

extern "C" void kernel_launch(void* const* d_in, const int* in_sizes, int n_in,
                              void* d_out, int out_size, void* d_ws, size_t ws_size,
                              hipStream_t stream) {
    const float* inputs = (const float*)d_in[0];   // [32][64][56][56]
    const float* kernel = (const float*)d_in[1];   // [1][4][576][128]
    const float* bias   = (const float*)d_in[2];   // [128]
    float* out          = (float*)d_out;           // [32][128][56][56]

    float*          part = (float*)d_ws;                          // 64 floats
    unsigned short* qwt  = (unsigned short*)((char*)d_ws + 512);  // 576 KiB packed

    absmax_part<<<64, 256, 0, stream>>>(kernel, part);
    quant_pack<<<(NW + 255) / 256, 256, 0, stream>>>(kernel, part, qwt);

    dim3 grid(2, NN, SW);   // 256 blocks = 1 per CU, 2 tiles each
    conv_mfma<<<grid, 512, 0, stream>>>(inputs, qwt, bias, out);
}

// Round 10
// 120.917 us; speedup vs baseline: 1.2109x; 1.2109x over previous
//
#include <hip/hip_runtime.h>
#include <hip/hip_bf16.h>

#define CIN   64
#define HH_   56
#define WW_   56
#define FOUT  128
#define NN    32
#define SW    4
#define WB    14
#define HB    14                     // output rows per tile
#define NW    (SW*9*FOUT*CIN)        // 294912 weights
#define QWT_PER_B (8*9*2*64*8)       // 73728 shorts per stripe

typedef __attribute__((ext_vector_type(8))) short bf16x8;
typedef __attribute__((ext_vector_type(4))) float f32x4;

__device__ inline unsigned short f2bf(float x) {
    unsigned u = __float_as_uint(x);
    return (unsigned short)((u + 0x7FFFu + ((u >> 16) & 1u)) >> 16);  // RNE
}

// ---------- kernel 1: partial absmax ----------
__global__ void absmax_part(const float* __restrict__ w, float* __restrict__ part) {
    __shared__ float sm[4];
    int tid = threadIdx.x;
    float m = 0.f;
    for (int idx = blockIdx.x * 256 + tid; idx < NW; idx += 64 * 256)
        m = fmaxf(m, fabsf(w[idx]));
    #pragma unroll
    for (int off = 32; off > 0; off >>= 1)
        m = fmaxf(m, __shfl_down(m, off, 64));
    if ((tid & 63) == 0) sm[tid >> 6] = m;
    __syncthreads();
    if (tid == 0)
        part[blockIdx.x] = fmaxf(fmaxf(sm[0], sm[1]), fmaxf(sm[2], sm[3]));
}

// ---------- kernel 2: quant + pack into MFMA A-fragment order ----------
// layout: qwt[b][ft][t][cc][lane][8]; content = qw[f = ft*16+(lane&15)]
//         [c = cc*32 + (lane>>4)*8 + r] for tap t.
__global__ void quant_pack(const float* __restrict__ w, const float* __restrict__ part,
                           unsigned short* __restrict__ qwt) {
    float pm = part[threadIdx.x & 63];
    #pragma unroll
    for (int off = 1; off < 64; off <<= 1)
        pm = fmaxf(pm, __shfl_xor(pm, off, 64));
    float scale = pm / 7.0f;
    int o = blockIdx.x * 256 + threadIdx.x;
    if (o >= NW) return;
    int r    = o & 7;
    int lane = (o >> 3) & 63;
    int cc   = (o >> 9) & 1;
    int idx  = o >> 10;            // b*72 + ft*9 + t
    int t    = idx % 9;
    int ft   = (idx / 9) & 7;
    int b    = idx / 72;
    int f = ft * 16 + (lane & 15);
    int c = cc * 32 + (lane >> 4) * 8 + r;
    float v = w[((b * CIN + c) * 9 + t) * FOUT + f];   // orig p = c*9 + t
    qwt[o] = f2bf(rintf(v / scale) * scale);
}

// ---------- kernel 3: persistent 2-tile conv, weights PINNED in registers ----------
// grid (2, 32, 4) = 256 blocks = 1/CU. Block: stripe b, tiles rows [h0a,h0a+14)
// and [h0b,h0b+14). 8 waves = (wf 0..3, wp 0..1): wave owns f-tiles {2wf,2wf+1}
// x 7 rows. One barrier; two pure ds_read+MFMA K-loops.
__global__ __launch_bounds__(512, 2)
void conv_mfma(const float* __restrict__ in,           // [N][C][H][W] f32
               const unsigned short* __restrict__ qwt, // packed A-fragments
               const float* __restrict__ bias,
               float* __restrict__ out) {              // [N][F][H][W] f32
    const int hp = blockIdx.x, n = blockIdx.y, b = blockIdx.z;
    const int w0 = b * WB;
    const int h0a = hp * 2 * HB, h0b = h0a + HB;
    const int tid = threadIdx.x;
    const int wave = tid >> 6, lane = tid & 63;
    const int q = lane >> 4, lm = lane & 15;
    const int wf = wave >> 1, wp = wave & 1;

    __shared__ __align__(16) unsigned short s_slab[2][256 * 64];   // 2 x 32 KiB

    // ---- weight A-fragments -> registers, ONCE, pinned live ----
    const unsigned short* wbase = qwt + (size_t)b * QWT_PER_B + lane * 8;
    bf16x8 wt[2][9][2];
    #pragma unroll
    for (int m = 0; m < 2; ++m)
        #pragma unroll
        for (int t = 0; t < 9; ++t)
            #pragma unroll
            for (int cc = 0; cc < 2; ++cc)
                wt[m][t][cc] = *(const bf16x8*)&wbase[((((wf * 2 + m) * 9) + t) * 2 + cc) * 512];

    // ---- stage BOTH slabs inline (load -> cvt -> ds_write; few live regs) ----
    #pragma unroll
    for (int s = 0; s < 2; ++s) {
        const int h0 = s ? h0b : h0a;
        #pragma unroll
        for (int i = 0; i < 16; ++i) {
            int e = i * 512 + tid;
            int cp = e & 15, c0 = ((e >> 4) & 31) * 2, row = e >> 9;
            int hi = h0 - 1 + row, wi = w0 - 1 + cp;
            float v0 = 0.f, v1 = 0.f;
            if (hi >= 0 && hi < HH_ && wi >= 0 && wi < WW_) {
                const float* p = &in[((n * CIN + c0) * HH_ + hi) * WW_ + wi];
                v0 = p[0]; v1 = p[HH_ * WW_];
            }
            unsigned pk = (unsigned)f2bf(v0) | ((unsigned)f2bf(v1) << 16);
            int pix = row * 16 + cp;
            *(unsigned*)&s_slab[s][pix * 64 + (c0 ^ ((cp & 7) << 3))] = pk;
        }
    }

    // ---- pin weights: black-box def+use so the compiler cannot sink/remat ----
    #pragma unroll
    for (int m = 0; m < 2; ++m)
        #pragma unroll
        for (int t = 0; t < 9; ++t)
            #pragma unroll
            for (int cc = 0; cc < 2; ++cc) {
                f32x4 tmp = __builtin_bit_cast(f32x4, wt[m][t][cc]);
                asm volatile("" : "+v"(tmp));
                wt[m][t][cc] = __builtin_bit_cast(bf16x8, tmp);
            }

    __syncthreads();   // the only barrier: both slabs ready

    f32x4 acc[2][7];
    #pragma unroll
    for (int s = 0; s < 2; ++s) {
        #pragma unroll
        for (int m = 0; m < 2; ++m)
            #pragma unroll
            for (int p = 0; p < 7; ++p)
                acc[m][p] = (f32x4){0.f, 0.f, 0.f, 0.f};

        // ---- K loop: 9 taps x 2 cc, pure ds_read + MFMA ----
        #pragma unroll
        for (int t = 0; t < 9; ++t) {
            const int kh = t / 3, kw = t - (t / 3) * 3;
            const int sc  = (lm + kw) & 15;
            const int swz = (sc & 7) << 3;
            #pragma unroll
            for (int cc = 0; cc < 2; ++cc) {
                const int koff = cc * 32 + q * 8;
                bf16x8 bfr[7];
                #pragma unroll
                for (int p = 0; p < 7; ++p) {
                    int srow = wp * 7 + p + kh;
                    bfr[p] = *(const bf16x8*)&s_slab[s][(srow * 16 + sc) * 64 + (koff ^ swz)];
                }
                #pragma unroll
                for (int m = 0; m < 2; ++m)
                    #pragma unroll
                    for (int p = 0; p < 7; ++p)
                        acc[m][p] = __builtin_amdgcn_mfma_f32_16x16x32_bf16(
                            wt[m][t][cc], bfr[p], acc[m][p], 0, 0, 0);
            }
        }

        // ---- epilogue (stores overlap next K-loop; no barrier needed) ----
        const int h0 = s ? h0b : h0a;
        if (lm < WB) {
            #pragma unroll
            for (int m = 0; m < 2; ++m) {
                #pragma unroll
                for (int r = 0; r < 4; ++r) {
                    int f = (wf * 2 + m) * 16 + q * 4 + r;
                    float bv = bias[f];
                    float* op = &out[(((size_t)n * FOUT + f) * HH_ + h0 + wp * 7) * WW_ + w0 + lm];
                    #pragma unroll
                    for (int p = 0; p < 7; ++p)
                        op[p * WW_] = acc[m][p][r] + bv;
                }
            }
        }
    }
}

extern "C" void kernel_launch(void* const* d_in, const int* in_sizes, int n_in,
                              void* d_out, int out_size, void* d_ws, size_t ws_size,
                              hipStream_t stream) {
    const float* inputs = (const float*)d_in[0];   // [32][64][56][56]
    const float* kernel = (const float*)d_in[1];   // [1][4][576][128]
    const float* bias   = (const float*)d_in[2];   // [128]
    float* out          = (float*)d_out;           // [32][128][56][56]

    float*          part = (float*)d_ws;                          // 64 floats
    unsigned short* qwt  = (unsigned short*)((char*)d_ws + 512);  // 576 KiB packed

    absmax_part<<<64, 256, 0, stream>>>(kernel, part);
    quant_pack<<<(NW + 255) / 256, 256, 0, stream>>>(kernel, part, qwt);

    dim3 grid(2, NN, SW);   // 256 blocks = 1 per CU, 2 tiles each
    conv_mfma<<<grid, 512, 0, stream>>>(inputs, qwt, bias, out);
}